// Round 25
// baseline (35.638 us; speedup 1.0000x reference)
//
#include <hip/hip_runtime.h>
#include <math.h>

typedef float f32x4 __attribute__((ext_vector_type(4)));
typedef _Float16 f16x8 __attribute__((ext_vector_type(8)));
typedef unsigned int u32;
typedef unsigned int u32x2 __attribute__((ext_vector_type(2)));
typedef unsigned int u32x4 __attribute__((ext_vector_type(4)));

#define MJ 64
#define HID 64
#define STR 144            // LDS row stride (128B payload + 16B skew)
#define TP 32              // points per wave tile
#define REGSZ (TP*STR)     // 4608B
#define SLICE (2*REGSZ)    // 9216B per wave (regions A+B)

// RNE f32->f16 pack (RTZ cvt_pkrtz is numerically fatal here: R20 measured
// 0.219 absmax from coherent toward-zero bias; RNE casts give 0.0156).
static __device__ __forceinline__ u32 pkhf(float a, float b) {
  unsigned short ua = __builtin_bit_cast(unsigned short, (_Float16)a);
  unsigned short ub = __builtin_bit_cast(unsigned short, (_Float16)b);
  return (u32)ua | ((u32)ub << 16);
}

static __device__ __forceinline__ f32x4 mfma16(f16x8 a, f16x8 b, f32x4 c) {
  return __builtin_amdgcn_mfma_f32_16x16x32_f16(a, b, c, 0, 0, 0);
}

// ws (f16): FT1[32][64] @0 | FT2[64][32] @4096B | FT3[64][64] @8192B
// FT1 feature f: 0-8 R row-major, 9-11 c=G0+trans-R*G0, 12-14 trans, 15 one,
//                16-31 wproj_w rows
// FT2[n][k]: k<19 = w1[n][k]; k==19 = b1[n]+sum_j w1[n][3+j]*wproj_b[j]; else 0
// FT3[n][k] = w2[n][k]
__global__ void rig_prep(const float* __restrict__ G0, const float* __restrict__ so3,
                         const float* __restrict__ trans, const float* __restrict__ wproj_w,
                         const float* __restrict__ wproj_b,
                         const float* __restrict__ w1, const float* __restrict__ b1,
                         const float* __restrict__ w2,
                         _Float16* __restrict__ FT1, _Float16* __restrict__ FT2,
                         _Float16* __restrict__ FT3) {
  const int t = threadIdx.x;  // 64 threads
  {
    const float ox = so3[3*t+0], oy = so3[3*t+1], oz = so3[3*t+2];
    const float th = sqrtf(ox*ox + oy*oy + oz*oz);
    float R[9];
    if (th < 1e-4f) {
      R[0]=1.f;  R[1]=-oz; R[2]=oy;
      R[3]=oz;   R[4]=1.f; R[5]=-ox;
      R[6]=-oy;  R[7]=ox;  R[8]=1.f;
    } else {
      const float it = 1.f/th;
      const float kx=ox*it, ky=oy*it, kz=oz*it;
      const float s=sinf(th), c=cosf(th), mc=1.f-c;
      R[0]=c+kx*kx*mc;     R[1]=kx*ky*mc-kz*s;  R[2]=kx*kz*mc+ky*s;
      R[3]=ky*kx*mc+kz*s;  R[4]=c+ky*ky*mc;     R[5]=ky*kz*mc-kx*s;
      R[6]=kz*kx*mc-ky*s;  R[7]=kz*ky*mc+kx*s;  R[8]=c+kz*kz*mc;
    }
    const float gx=G0[3*t], gy=G0[3*t+1], gz=G0[3*t+2];
    const float tx=trans[3*t], ty=trans[3*t+1], tz=trans[3*t+2];
    float feat[32];
    #pragma unroll
    for (int i=0;i<9;i++) feat[i]=R[i];
    feat[9]  = gx + tx - (R[0]*gx + R[1]*gy + R[2]*gz);
    feat[10] = gy + ty - (R[3]*gx + R[4]*gy + R[5]*gz);
    feat[11] = gz + tz - (R[6]*gx + R[7]*gy + R[8]*gz);
    feat[12]=tx; feat[13]=ty; feat[14]=tz;
    feat[15]=1.0f;
    #pragma unroll
    for (int i=0;i<16;i++) feat[16+i] = wproj_w[i*MJ + t];
    #pragma unroll
    for (int f=0;f<32;f++) FT1[f*64 + t] = (_Float16)feat[f];
  }
  {
    float fold = b1[t];
    #pragma unroll
    for (int j=0;j<16;j++) fold = fmaf(w1[t*19 + 3 + j], wproj_b[j], fold);
    #pragma unroll
    for (int k=0;k<19;k++) FT2[t*32+k] = (_Float16)w1[t*19+k];
    FT2[t*32+19] = (_Float16)fold;
    #pragma unroll
    for (int k=20;k<32;k++) FT2[t*32+k] = (_Float16)0.0f;
  }
  for (int k=0;k<64;k++) FT3[t*64+k] = (_Float16)w2[t*64+k];
}

// 4 waves x 32 points (R13-verified skeleton) + R22-verified direct-global P1.
// Per wave: disjoint ping-pong LDS regions A,B (4608B each, 32 rows x 144B);
// every phase reads one region, writes ONLY the other; plain __syncthreads()
// between phases. 4 blocks/CU (LDS 36864/block).
//   P1: G1 reads global W (reg-pack f16), acc->B | P2: epilogue reads B, hin->A
//   P3: G2 reads A, h1->B | P4: G3 reads B, h2->A | P5: L3 reads A -> out
// Lanes 32-63 duplicate lanes 0-31 in per-point phases (same values; benign).
__global__ __launch_bounds__(256, 4)
void rig_main(const float* __restrict__ X0, const float* __restrict__ W,
              const _Float16* __restrict__ FT1, const _Float16* __restrict__ FT2,
              const _Float16* __restrict__ FT3,
              const float* __restrict__ b2, const float* __restrict__ w3,
              const float* __restrict__ b3,
              float* __restrict__ out, int Ntot) {
  __shared__ __align__(16) unsigned char smem[4*SLICE];   // 36864B
  const int tid  = threadIdx.x;
  const int wid  = tid >> 6;
  const int lane = tid & 63;
  const int lo   = lane & 15;
  const int hi   = lane >> 4;
  const int pl   = lane & 31;                    // point index within tile
  const int P0   = blockIdx.x * (4*TP) + wid * TP;
  unsigned char* Areg = smem + wid * SLICE;
  unsigned char* Breg = Areg + REGSZ;

  const float x0 = X0[(size_t)(P0+pl)*3+0];
  const float x1 = X0[(size_t)(P0+pl)*3+1];
  const float x2 = X0[(size_t)(P0+pl)*3+2];

  // ---- P1: G1  C[feat 32][pt 32] = FT1(32x64) @ Wg^T, K=64 ; acc -> B
  //      B-fragment (pt,ks) = f16(W[P0+pt*16+lo][ks*32+hi*8 .. +7]) from global
  {
    f16x8 a1[2][2];
    #pragma unroll
    for (int ft=0; ft<2; ft++)
      #pragma unroll
      for (int ks=0; ks<2; ks++)
        a1[ft][ks] = *(const f16x8*)(FT1 + (ft*16+lo)*64 + ks*32 + hi*8);
    f32x4 acc[2][2];
    const f32x4 z = {0.f,0.f,0.f,0.f};
    #pragma unroll
    for (int ft=0; ft<2; ft++)
      #pragma unroll
      for (int pt=0; pt<2; pt++) acc[ft][pt] = z;

    const float* Wl = W + (size_t)(P0 + lo) * MJ + hi*8;
    #pragma unroll
    for (int pt=0; pt<2; pt++) {
      const float* Wp = Wl + (size_t)pt*16*MJ;
      f16x8 bf[2];
      #pragma unroll
      for (int ks=0; ks<2; ks++) {
        f32x4 q0 = *(const f32x4*)(Wp + ks*32);
        f32x4 q1 = *(const f32x4*)(Wp + ks*32 + 4);
        u32x4 pk;
        pk.x = pkhf(q0[0], q0[1]); pk.y = pkhf(q0[2], q0[3]);
        pk.z = pkhf(q1[0], q1[1]); pk.w = pkhf(q1[2], q1[3]);
        bf[ks] = __builtin_bit_cast(f16x8, pk);
      }
      #pragma unroll
      for (int ks=0; ks<2; ks++) {
        acc[0][pt] = mfma16(a1[0][ks], bf[ks], acc[0][pt]);
        acc[1][pt] = mfma16(a1[1][ks], bf[ks], acc[1][pt]);
      }
    }
    // D reg r of lane (hi,lo) = C[feat ft*16+hi*4+r][pt pt*16+lo] -> region B
    #pragma unroll
    for (int pt=0; pt<2; pt++)
      #pragma unroll
      for (int ft=0; ft<2; ft++)
        *(f32x4*)(Breg + (pt*16+lo)*STR + ft*64 + hi*16) = acc[ft][pt];
  }
  __syncthreads();

  // ---- P2: per-point epilogue (reads B row pl) -> hin f16 row in A
  float Rb[9], sk0, sk1, sk2;
  {
    float v[32];
    #pragma unroll
    for (int i=0;i<8;i++) {
      f32x4 t4 = *(const f32x4*)(Breg + pl*STR + i*16);
      v[4*i+0]=t4[0]; v[4*i+1]=t4[1]; v[4*i+2]=t4[2]; v[4*i+3]=t4[3];
    }
    const float inv = 1.0f/(v[15] + 1e-12f);
    #pragma unroll
    for (int i=0;i<9;i++) Rb[i]=v[i]*inv;
    const float cb0=v[9]*inv,  cb1=v[10]*inv, cb2=v[11]*inv;
    const float tb0=v[12]*inv, tb1=v[13]*inv, tb2=v[14]*inv;
    sk0 = fmaf(Rb[0],x0, fmaf(Rb[1],x1, fmaf(Rb[2],x2, cb0)));
    sk1 = fmaf(Rb[3],x0, fmaf(Rb[4],x1, fmaf(Rb[5],x2, cb1)));
    sk2 = fmaf(Rb[6],x0, fmaf(Rb[7],x1, fmaf(Rb[8],x2, cb2)));
    const float u0=sk0-tb0, u1=sk1-tb1, u2=sk2-tb2;
    const float l0 = Rb[0]*u0 + Rb[3]*u1 + Rb[6]*u2;
    const float l1 = Rb[1]*u0 + Rb[4]*u1 + Rb[7]*u2;
    const float l2 = Rb[2]*u0 + Rb[5]*u1 + Rb[8]*u2;
    float wf[16];
    #pragma unroll
    for (int j=0;j<16;j++) wf[j] = v[16+j]*inv;   // wproj_b folded into FT2 k=19
    u32x4 h0, h1v, h2v, h3;
    h0.x = pkhf(l0, l1);       h0.y = pkhf(l2, wf[0]);
    h0.z = pkhf(wf[1], wf[2]); h0.w = pkhf(wf[3], wf[4]);
    h1v.x = pkhf(wf[5], wf[6]);  h1v.y = pkhf(wf[7], wf[8]);
    h1v.z = pkhf(wf[9], wf[10]); h1v.w = pkhf(wf[11], wf[12]);
    h2v.x = pkhf(wf[13], wf[14]); h2v.y = pkhf(wf[15], 1.0f);
    h2v.z = 0u; h2v.w = 0u;
    h3.x = 0u; h3.y = 0u; h3.z = 0u; h3.w = 0u;
    // lanes 32-63 write the same bytes with the same values (benign)
    *(u32x4*)(Areg + pl*STR +  0) = h0;
    *(u32x4*)(Areg + pl*STR + 16) = h1v;
    *(u32x4*)(Areg + pl*STR + 32) = h2v;
    *(u32x4*)(Areg + pl*STR + 48) = h3;
  }
  __syncthreads();

  // ---- P3: G2  h1[n 64][pt 32] = FT2(64x32) @ hin^T, K=32 ; h1 -> B
  {
    f16x8 bh[2];
    #pragma unroll
    for (int pt=0; pt<2; pt++)
      bh[pt] = *(const f16x8*)(Areg + (pt*16+lo)*STR + hi*16);
    #pragma unroll
    for (int nh=0; nh<2; nh++) {
      f16x8 a2[2];
      #pragma unroll
      for (int n2=0; n2<2; n2++)
        a2[n2] = *(const f16x8*)(FT2 + ((nh*2+n2)*16+lo)*32 + hi*8);
      f32x4 c2[2][2];
      const f32x4 z = {0.f,0.f,0.f,0.f};
      #pragma unroll
      for (int n2=0;n2<2;n2++)
        #pragma unroll
        for (int pt=0;pt<2;pt++) c2[n2][pt] = z;
      #pragma unroll
      for (int pt=0; pt<2; pt++)
        #pragma unroll
        for (int n2=0; n2<2; n2++)
          c2[n2][pt] = mfma16(a2[n2], bh[pt], c2[n2][pt]);
      #pragma unroll
      for (int n2=0; n2<2; n2++)
        #pragma unroll
        for (int pt=0; pt<2; pt++) {
          f32x4 r = c2[n2][pt];
          u32x2 wv;
          wv.x = pkhf(fmaxf(r[0],0.f), fmaxf(r[1],0.f));
          wv.y = pkhf(fmaxf(r[2],0.f), fmaxf(r[3],0.f));
          *(u32x2*)(Breg + (pt*16+lo)*STR + (nh*2+n2)*32 + hi*8) = wv;
        }
    }
  }
  __syncthreads();

  // ---- P4: G3  h2[n 64][pt 32] = FT3(64x64) @ h1^T, K=64, +b2, relu ; h2 -> A
  {
    f16x8 bh1[2][2];
    #pragma unroll
    for (int pt=0; pt<2; pt++)
      #pragma unroll
      for (int ks=0; ks<2; ks++)
        bh1[pt][ks] = *(const f16x8*)(Breg + (pt*16+lo)*STR + ks*64 + hi*16);
    #pragma unroll
    for (int nh=0; nh<2; nh++) {
      f16x8 a3[2][2];
      #pragma unroll
      for (int n2=0; n2<2; n2++)
        #pragma unroll
        for (int ks=0; ks<2; ks++)
          a3[n2][ks] = *(const f16x8*)(FT3 + ((nh*2+n2)*16+lo)*64 + ks*32 + hi*8);
      f32x4 c3[2][2];
      const f32x4 z = {0.f,0.f,0.f,0.f};
      #pragma unroll
      for (int n2=0;n2<2;n2++)
        #pragma unroll
        for (int pt=0;pt<2;pt++) c3[n2][pt] = z;
      #pragma unroll
      for (int pt=0; pt<2; pt++)
        #pragma unroll
        for (int ks=0; ks<2; ks++)
          #pragma unroll
          for (int n2=0; n2<2; n2++)
            c3[n2][pt] = mfma16(a3[n2][ks], bh1[pt][ks], c3[n2][pt]);
      #pragma unroll
      for (int n2=0; n2<2; n2++) {
        const f32x4 vb2 = *(const f32x4*)(b2 + (nh*2+n2)*16 + hi*4);
        #pragma unroll
        for (int pt=0; pt<2; pt++) {
          f32x4 r = c3[n2][pt];
          u32x2 wv;
          wv.x = pkhf(fmaxf(r[0]+vb2[0],0.f), fmaxf(r[1]+vb2[1],0.f));
          wv.y = pkhf(fmaxf(r[2]+vb2[2],0.f), fmaxf(r[3]+vb2[3],0.f));
          *(u32x2*)(Areg + (pt*16+lo)*STR + (nh*2+n2)*32 + hi*8) = wv;
        }
      }
    }
  }
  __syncthreads();

  // ---- P5: scalar L3 (reads A row pl; w3 wave-uniform -> s_load) + out
  {
    float d0 = b3[0], d1 = b3[1], d2 = b3[2];
    #pragma unroll
    for (int i8=0; i8<8; i8++) {
      f16x8 hv = *(const f16x8*)(Areg + pl*STR + i8*16);
      #pragma unroll
      for (int e=0; e<8; e++) {
        const float a = (float)hv[e];     // already relu'd
        const int j = i8*8 + e;
        d0 = fmaf(a, w3[      j], d0);
        d1 = fmaf(a, w3[ 64 + j], d1);
        d2 = fmaf(a, w3[128 + j], d2);
      }
    }
    if (lane < TP) {
      const float dw0 = Rb[0]*d0 + Rb[1]*d1 + Rb[2]*d2;
      const float dw1 = Rb[3]*d0 + Rb[4]*d1 + Rb[5]*d2;
      const float dw2 = Rb[6]*d0 + Rb[7]*d1 + Rb[8]*d2;
      const size_t o = (size_t)(P0+pl)*3;
      out[o+0] = sk0 + dw0;
      out[o+1] = sk1 + dw1;
      out[o+2] = sk2 + dw2;
    }
  }
}

extern "C" void kernel_launch(void* const* d_in, const int* in_sizes, int n_in,
                              void* d_out, int out_size, void* d_ws, size_t ws_size,
                              hipStream_t stream) {
  const float* X0      = (const float*)d_in[0];
  const float* G0      = (const float*)d_in[1];
  const float* W       = (const float*)d_in[2];
  const float* so3     = (const float*)d_in[3];
  const float* trans   = (const float*)d_in[4];
  const float* wproj_w = (const float*)d_in[5];
  const float* wproj_b = (const float*)d_in[6];
  const float* w1      = (const float*)d_in[7];
  const float* b1      = (const float*)d_in[8];
  const float* w2      = (const float*)d_in[9];
  const float* b2      = (const float*)d_in[10];
  const float* w3      = (const float*)d_in[11];
  const float* b3      = (const float*)d_in[12];
  float* out = (float*)d_out;

  const int Ntot = in_sizes[0] / 3;   // 262144 = 2048 blocks * 128 pts

  _Float16* FT1 = (_Float16*)d_ws;                      // 4096B
  _Float16* FT2 = (_Float16*)((char*)d_ws + 4096);      // 4096B
  _Float16* FT3 = (_Float16*)((char*)d_ws + 8192);      // 8192B

  rig_prep<<<1, 64, 0, stream>>>(G0, so3, trans, wproj_w, wproj_b,
                                 w1, b1, w2, FT1, FT2, FT3);
  rig_main<<<Ntot/(4*TP), 256, 0, stream>>>(X0, W, FT1, FT2, FT3,
                                            b2, w3, b3, out, Ntot);
}

// Round 26
// 31.969 us; speedup vs baseline: 1.1148x; 1.1148x over previous
//
#include <hip/hip_runtime.h>
#include <math.h>

typedef float f32x4 __attribute__((ext_vector_type(4)));
typedef _Float16 f16x8 __attribute__((ext_vector_type(8)));
typedef unsigned int u32;
typedef unsigned int u32x2 __attribute__((ext_vector_type(2)));
typedef unsigned int u32x4 __attribute__((ext_vector_type(4)));

#define MJ 64
#define HID 64
#define STR 144            // LDS row stride (128B payload + 16B bank skew)
#define REGSZ 9216         // one region = 64 rows * 144B
#define SLICE 18432        // per-wave slice = region A + region B

// RNE f32->f16 pack (RTZ cvt_pkrtz is numerically fatal here: R20 measured
// 0.219 absmax from coherent toward-zero bias; RNE casts give 0.0156).
static __device__ __forceinline__ u32 pkhf(float a, float b) {
  unsigned short ua = __builtin_bit_cast(unsigned short, (_Float16)a);
  unsigned short ub = __builtin_bit_cast(unsigned short, (_Float16)b);
  return (u32)ua | ((u32)ub << 16);
}

static __device__ __forceinline__ f32x4 mfma16(f16x8 a, f16x8 b, f32x4 c) {
  return __builtin_amdgcn_mfma_f32_16x16x32_f16(a, b, c, 0, 0, 0);
}

// ws (f16): FT1[32][64] @0 | FT2[64][32] @4096B | FT3[64][64] @8192B
// FT1 feature f: 0-8 R row-major, 9-11 c=G0+trans-R*G0, 12-14 trans, 15 one,
//                16-31 wproj_w rows
// FT2[n][k]: k<19 = w1[n][k]; k==19 = b1[n]+sum_j w1[n][3+j]*wproj_b[j]; else 0
// FT3[n][k] = w2[n][k]
__global__ void rig_prep(const float* __restrict__ G0, const float* __restrict__ so3,
                         const float* __restrict__ trans, const float* __restrict__ wproj_w,
                         const float* __restrict__ wproj_b,
                         const float* __restrict__ w1, const float* __restrict__ b1,
                         const float* __restrict__ w2,
                         _Float16* __restrict__ FT1, _Float16* __restrict__ FT2,
                         _Float16* __restrict__ FT3) {
  const int t = threadIdx.x;  // 64 threads
  {
    const float ox = so3[3*t+0], oy = so3[3*t+1], oz = so3[3*t+2];
    const float th = sqrtf(ox*ox + oy*oy + oz*oz);
    float R[9];
    if (th < 1e-4f) {
      R[0]=1.f;  R[1]=-oz; R[2]=oy;
      R[3]=oz;   R[4]=1.f; R[5]=-ox;
      R[6]=-oy;  R[7]=ox;  R[8]=1.f;
    } else {
      const float it = 1.f/th;
      const float kx=ox*it, ky=oy*it, kz=oz*it;
      const float s=sinf(th), c=cosf(th), mc=1.f-c;
      R[0]=c+kx*kx*mc;     R[1]=kx*ky*mc-kz*s;  R[2]=kx*kz*mc+ky*s;
      R[3]=ky*kx*mc+kz*s;  R[4]=c+ky*ky*mc;     R[5]=ky*kz*mc-kx*s;
      R[6]=kz*kx*mc-ky*s;  R[7]=kz*ky*mc+kx*s;  R[8]=c+kz*kz*mc;
    }
    const float gx=G0[3*t], gy=G0[3*t+1], gz=G0[3*t+2];
    const float tx=trans[3*t], ty=trans[3*t+1], tz=trans[3*t+2];
    float feat[32];
    #pragma unroll
    for (int i=0;i<9;i++) feat[i]=R[i];
    feat[9]  = gx + tx - (R[0]*gx + R[1]*gy + R[2]*gz);
    feat[10] = gy + ty - (R[3]*gx + R[4]*gy + R[5]*gz);
    feat[11] = gz + tz - (R[6]*gx + R[7]*gy + R[8]*gz);
    feat[12]=tx; feat[13]=ty; feat[14]=tz;
    feat[15]=1.0f;
    #pragma unroll
    for (int i=0;i<16;i++) feat[16+i] = wproj_w[i*MJ + t];
    #pragma unroll
    for (int f=0;f<32;f++) FT1[f*64 + t] = (_Float16)feat[f];
  }
  {
    float fold = b1[t];
    #pragma unroll
    for (int j=0;j<16;j++) fold = fmaf(w1[t*19 + 3 + j], wproj_b[j], fold);
    #pragma unroll
    for (int k=0;k<19;k++) FT2[t*32+k] = (_Float16)w1[t*19+k];
    FT2[t*32+19] = (_Float16)fold;
    #pragma unroll
    for (int k=20;k<32;k++) FT2[t*32+k] = (_Float16)0.0f;
  }
  for (int k=0;k<64;k++) FT3[t*64+k] = (_Float16)w2[t*64+k];
}

// 4 waves x 64 points (verified ping-pong skeleton, no W LDS staging):
// G1's B-operand (W fragments) loads directly from global (32 contiguous
// bytes/lane, full 128B lines) and packs to f16 in registers.
//   P1: G1 reads global W, acc->B | P2: epilogue reads B, hin->A
//   P3: G2 reads A, h1->B | P4: G3 reads B, h2->A | P5: L3 reads A -> out
__global__ __launch_bounds__(256, 2)
void rig_main(const float* __restrict__ X0, const float* __restrict__ W,
              const _Float16* __restrict__ FT1, const _Float16* __restrict__ FT2,
              const _Float16* __restrict__ FT3,
              const float* __restrict__ b2, const float* __restrict__ w3,
              const float* __restrict__ b3,
              float* __restrict__ out, int Ntot) {
  __shared__ __align__(16) unsigned char smem[4*SLICE];   // 73728B
  const int tid  = threadIdx.x;
  const int wid  = tid >> 6;
  const int lane = tid & 63;
  const int lo   = lane & 15;
  const int hi   = lane >> 4;
  const int P0   = blockIdx.x * 256 + wid * 64;
  unsigned char* Areg = smem + wid * SLICE;
  unsigned char* Breg = Areg + REGSZ;

  const float x0 = X0[(size_t)(P0+lane)*3+0];
  const float x1 = X0[(size_t)(P0+lane)*3+1];
  const float x2 = X0[(size_t)(P0+lane)*3+2];

  // ---- P1: G1  C[feat 32][pt 64] = FT1(32x64) @ Wg^T, K=64 ; acc -> B
  //      B-fragment (pt,ks) = f16(W[P0+pt*16+lo][ks*32+hi*8 .. +7]) from global
  {
    f16x8 a1[2][2];
    #pragma unroll
    for (int ft=0; ft<2; ft++)
      #pragma unroll
      for (int ks=0; ks<2; ks++)
        a1[ft][ks] = *(const f16x8*)(FT1 + (ft*16+lo)*64 + ks*32 + hi*8);
    f32x4 acc[2][4];
    const f32x4 z = {0.f,0.f,0.f,0.f};
    #pragma unroll
    for (int ft=0; ft<2; ft++)
      #pragma unroll
      for (int pt=0; pt<4; pt++) acc[ft][pt] = z;

    const float* Wl = W + (size_t)(P0 + lo) * MJ + hi*8;
    #pragma unroll
    for (int pt=0; pt<4; pt++) {
      const float* Wp = Wl + (size_t)pt*16*MJ;
      f16x8 bf[2];
      #pragma unroll
      for (int ks=0; ks<2; ks++) {
        f32x4 q0 = *(const f32x4*)(Wp + ks*32);
        f32x4 q1 = *(const f32x4*)(Wp + ks*32 + 4);
        u32x4 pk;
        pk.x = pkhf(q0[0], q0[1]); pk.y = pkhf(q0[2], q0[3]);
        pk.z = pkhf(q1[0], q1[1]); pk.w = pkhf(q1[2], q1[3]);
        bf[ks] = __builtin_bit_cast(f16x8, pk);
      }
      #pragma unroll
      for (int ks=0; ks<2; ks++) {
        acc[0][pt] = mfma16(a1[0][ks], bf[ks], acc[0][pt]);
        acc[1][pt] = mfma16(a1[1][ks], bf[ks], acc[1][pt]);
      }
    }
    // D reg r of lane (hi,lo) = C[feat ft*16+hi*4+r][pt pt*16+lo] -> region B
    #pragma unroll
    for (int pt=0; pt<4; pt++)
      #pragma unroll
      for (int ft=0; ft<2; ft++)
        *(f32x4*)(Breg + (pt*16+lo)*STR + ft*64 + hi*16) = acc[ft][pt];
  }
  __syncthreads();

  // ---- P2: per-point epilogue (reads B own row) -> hin f16 row in A
  float Rb[9], sk0, sk1, sk2;
  {
    float v[32];
    #pragma unroll
    for (int i=0;i<8;i++) {
      f32x4 t4 = *(const f32x4*)(Breg + lane*STR + i*16);
      v[4*i+0]=t4[0]; v[4*i+1]=t4[1]; v[4*i+2]=t4[2]; v[4*i+3]=t4[3];
    }
    const float inv = 1.0f/(v[15] + 1e-12f);
    #pragma unroll
    for (int i=0;i<9;i++) Rb[i]=v[i]*inv;
    const float cb0=v[9]*inv,  cb1=v[10]*inv, cb2=v[11]*inv;
    const float tb0=v[12]*inv, tb1=v[13]*inv, tb2=v[14]*inv;
    sk0 = fmaf(Rb[0],x0, fmaf(Rb[1],x1, fmaf(Rb[2],x2, cb0)));
    sk1 = fmaf(Rb[3],x0, fmaf(Rb[4],x1, fmaf(Rb[5],x2, cb1)));
    sk2 = fmaf(Rb[6],x0, fmaf(Rb[7],x1, fmaf(Rb[8],x2, cb2)));
    const float u0=sk0-tb0, u1=sk1-tb1, u2=sk2-tb2;
    const float l0 = Rb[0]*u0 + Rb[3]*u1 + Rb[6]*u2;
    const float l1 = Rb[1]*u0 + Rb[4]*u1 + Rb[7]*u2;
    const float l2 = Rb[2]*u0 + Rb[5]*u1 + Rb[8]*u2;
    float wf[16];
    #pragma unroll
    for (int j=0;j<16;j++) wf[j] = v[16+j]*inv;   // wproj_b folded into FT2 k=19
    u32x4 h0, h1v, h2v, h3;
    h0.x = pkhf(l0, l1);       h0.y = pkhf(l2, wf[0]);
    h0.z = pkhf(wf[1], wf[2]); h0.w = pkhf(wf[3], wf[4]);
    h1v.x = pkhf(wf[5], wf[6]);  h1v.y = pkhf(wf[7], wf[8]);
    h1v.z = pkhf(wf[9], wf[10]); h1v.w = pkhf(wf[11], wf[12]);
    h2v.x = pkhf(wf[13], wf[14]); h2v.y = pkhf(wf[15], 1.0f);
    h2v.z = 0u; h2v.w = 0u;
    h3.x = 0u; h3.y = 0u; h3.z = 0u; h3.w = 0u;
    *(u32x4*)(Areg + lane*STR +  0) = h0;
    *(u32x4*)(Areg + lane*STR + 16) = h1v;
    *(u32x4*)(Areg + lane*STR + 32) = h2v;
    *(u32x4*)(Areg + lane*STR + 48) = h3;
  }
  __syncthreads();

  // ---- P3: G2  h1[n 64][pt 64] = FT2(64x32) @ hin^T, K=32 ; h1 -> B
  {
    f16x8 bh[4];
    #pragma unroll
    for (int pt=0; pt<4; pt++)
      bh[pt] = *(const f16x8*)(Areg + (pt*16+lo)*STR + hi*16);
    #pragma unroll
    for (int nh=0; nh<2; nh++) {
      f16x8 a2[2];
      #pragma unroll
      for (int n2=0; n2<2; n2++)
        a2[n2] = *(const f16x8*)(FT2 + ((nh*2+n2)*16+lo)*32 + hi*8);
      f32x4 c2[2][4];
      const f32x4 z = {0.f,0.f,0.f,0.f};
      #pragma unroll
      for (int n2=0;n2<2;n2++)
        #pragma unroll
        for (int pt=0;pt<4;pt++) c2[n2][pt] = z;
      #pragma unroll
      for (int pt=0; pt<4; pt++)
        #pragma unroll
        for (int n2=0; n2<2; n2++)
          c2[n2][pt] = mfma16(a2[n2], bh[pt], c2[n2][pt]);
      #pragma unroll
      for (int n2=0; n2<2; n2++)
        #pragma unroll
        for (int pt=0; pt<4; pt++) {
          f32x4 r = c2[n2][pt];
          u32x2 wv;
          wv.x = pkhf(fmaxf(r[0],0.f), fmaxf(r[1],0.f));
          wv.y = pkhf(fmaxf(r[2],0.f), fmaxf(r[3],0.f));
          *(u32x2*)(Breg + (pt*16+lo)*STR + (nh*2+n2)*32 + hi*8) = wv;
        }
    }
  }
  __syncthreads();

  // ---- P4: G3  h2[n 64][pt 64] = FT3(64x64) @ h1^T, K=64, +b2, relu ; h2 -> A
  {
    f16x8 bh1[4][2];
    #pragma unroll
    for (int pt=0; pt<4; pt++)
      #pragma unroll
      for (int ks=0; ks<2; ks++)
        bh1[pt][ks] = *(const f16x8*)(Breg + (pt*16+lo)*STR + ks*64 + hi*16);
    #pragma unroll
    for (int nh=0; nh<2; nh++) {
      f16x8 a3[2][2];
      #pragma unroll
      for (int n2=0; n2<2; n2++)
        #pragma unroll
        for (int ks=0; ks<2; ks++)
          a3[n2][ks] = *(const f16x8*)(FT3 + ((nh*2+n2)*16+lo)*64 + ks*32 + hi*8);
      f32x4 c3[2][4];
      const f32x4 z = {0.f,0.f,0.f,0.f};
      #pragma unroll
      for (int n2=0;n2<2;n2++)
        #pragma unroll
        for (int pt=0;pt<4;pt++) c3[n2][pt] = z;
      #pragma unroll
      for (int pt=0; pt<4; pt++)
        #pragma unroll
        for (int ks=0; ks<2; ks++)
          #pragma unroll
          for (int n2=0; n2<2; n2++)
            c3[n2][pt] = mfma16(a3[n2][ks], bh1[pt][ks], c3[n2][pt]);
      #pragma unroll
      for (int n2=0; n2<2; n2++) {
        const f32x4 vb2 = *(const f32x4*)(b2 + (nh*2+n2)*16 + hi*4);
        #pragma unroll
        for (int pt=0; pt<4; pt++) {
          f32x4 r = c3[n2][pt];
          u32x2 wv;
          wv.x = pkhf(fmaxf(r[0]+vb2[0],0.f), fmaxf(r[1]+vb2[1],0.f));
          wv.y = pkhf(fmaxf(r[2]+vb2[2],0.f), fmaxf(r[3]+vb2[3],0.f));
          *(u32x2*)(Areg + (pt*16+lo)*STR + (nh*2+n2)*32 + hi*8) = wv;
        }
      }
    }
  }
  __syncthreads();

  // ---- P5: scalar L3 (reads A own row; w3 wave-uniform -> s_load) + out
  {
    float d0 = b3[0], d1 = b3[1], d2 = b3[2];
    #pragma unroll
    for (int i8=0; i8<8; i8++) {
      f16x8 hv = *(const f16x8*)(Areg + lane*STR + i8*16);
      #pragma unroll
      for (int e=0; e<8; e++) {
        const float a = (float)hv[e];     // already relu'd
        const int j = i8*8 + e;
        d0 = fmaf(a, w3[      j], d0);
        d1 = fmaf(a, w3[ 64 + j], d1);
        d2 = fmaf(a, w3[128 + j], d2);
      }
    }
    const float dw0 = Rb[0]*d0 + Rb[1]*d1 + Rb[2]*d2;
    const float dw1 = Rb[3]*d0 + Rb[4]*d1 + Rb[5]*d2;
    const float dw2 = Rb[6]*d0 + Rb[7]*d1 + Rb[8]*d2;
    const size_t o = (size_t)(P0+lane)*3;
    out[o+0] = sk0 + dw0;
    out[o+1] = sk1 + dw1;
    out[o+2] = sk2 + dw2;
  }
}

extern "C" void kernel_launch(void* const* d_in, const int* in_sizes, int n_in,
                              void* d_out, int out_size, void* d_ws, size_t ws_size,
                              hipStream_t stream) {
  const float* X0      = (const float*)d_in[0];
  const float* G0      = (const float*)d_in[1];
  const float* W       = (const float*)d_in[2];
  const float* so3     = (const float*)d_in[3];
  const float* trans   = (const float*)d_in[4];
  const float* wproj_w = (const float*)d_in[5];
  const float* wproj_b = (const float*)d_in[6];
  const float* w1      = (const float*)d_in[7];
  const float* b1      = (const float*)d_in[8];
  const float* w2      = (const float*)d_in[9];
  const float* b2      = (const float*)d_in[10];
  const float* w3      = (const float*)d_in[11];
  const float* b3      = (const float*)d_in[12];
  float* out = (float*)d_out;

  const int Ntot = in_sizes[0] / 3;   // 262144

  _Float16* FT1 = (_Float16*)d_ws;                      // 4096B
  _Float16* FT2 = (_Float16*)((char*)d_ws + 4096);      // 4096B
  _Float16* FT3 = (_Float16*)((char*)d_ws + 8192);      // 8192B

  rig_prep<<<1, 64, 0, stream>>>(G0, so3, trans, wproj_w, wproj_b,
                                 w1, b1, w2, FT1, FT2, FT3);
  rig_main<<<Ntot/256, 256, 0, stream>>>(X0, W, FT1, FT2, FT3,
                                         b2, w3, b3, out, Ntot);
}

// Round 27
// 30.224 us; speedup vs baseline: 1.1791x; 1.0577x over previous
//
#include <hip/hip_runtime.h>
#include <math.h>

typedef float f32x4 __attribute__((ext_vector_type(4)));
typedef _Float16 f16x8 __attribute__((ext_vector_type(8)));
typedef unsigned int u32;
typedef unsigned int u32x2 __attribute__((ext_vector_type(2)));
typedef unsigned int u32x4 __attribute__((ext_vector_type(4)));

#define MJ 64
#define HID 64
#define STR 144            // LDS row stride (128B payload + 16B bank skew)
#define REGSZ 9216         // one region = 64 rows * 144B
#define SLICE 18432        // per-wave slice = region A + region B

// RNE f32->f16 pack (RTZ cvt_pkrtz is numerically fatal here: R20 measured
// 0.219 absmax from coherent toward-zero bias; RNE casts give 0.0156).
static __device__ __forceinline__ u32 pkhf(float a, float b) {
  unsigned short ua = __builtin_bit_cast(unsigned short, (_Float16)a);
  unsigned short ub = __builtin_bit_cast(unsigned short, (_Float16)b);
  return (u32)ua | ((u32)ub << 16);
}

static __device__ __forceinline__ f32x4 mfma16(f16x8 a, f16x8 b, f32x4 c) {
  return __builtin_amdgcn_mfma_f32_16x16x32_f16(a, b, c, 0, 0, 0);
}

// Compile-time phase fence (R17-validated discipline): all LDS traffic is
// wave-private (per-wave A/B slices), so no runtime barrier is needed —
// the HW DS pipe is in-order per wave and the compiler tracks its own
// ds_read->use lgkmcnt. The fence only pins phase order against compiler
// motion. Removing s_barrier lets the block's 4 waves free-run, staggering
// their load-heavy P1 phases against other waves' compute phases.
static __device__ __forceinline__ void phase_fence() {
  __builtin_amdgcn_sched_barrier(0);
}

// ws (f16): FT1[32][64] @0 | FT2[64][32] @4096B | FT3[64][64] @8192B
// FT1 feature f: 0-8 R row-major, 9-11 c=G0+trans-R*G0, 12-14 trans, 15 one,
//                16-31 wproj_w rows
// FT2[n][k]: k<19 = w1[n][k]; k==19 = b1[n]+sum_j w1[n][3+j]*wproj_b[j]; else 0
// FT3[n][k] = w2[n][k]
__global__ void rig_prep(const float* __restrict__ G0, const float* __restrict__ so3,
                         const float* __restrict__ trans, const float* __restrict__ wproj_w,
                         const float* __restrict__ wproj_b,
                         const float* __restrict__ w1, const float* __restrict__ b1,
                         const float* __restrict__ w2,
                         _Float16* __restrict__ FT1, _Float16* __restrict__ FT2,
                         _Float16* __restrict__ FT3) {
  const int t = threadIdx.x;  // 64 threads
  {
    const float ox = so3[3*t+0], oy = so3[3*t+1], oz = so3[3*t+2];
    const float th = sqrtf(ox*ox + oy*oy + oz*oz);
    float R[9];
    if (th < 1e-4f) {
      R[0]=1.f;  R[1]=-oz; R[2]=oy;
      R[3]=oz;   R[4]=1.f; R[5]=-ox;
      R[6]=-oy;  R[7]=ox;  R[8]=1.f;
    } else {
      const float it = 1.f/th;
      const float kx=ox*it, ky=oy*it, kz=oz*it;
      const float s=sinf(th), c=cosf(th), mc=1.f-c;
      R[0]=c+kx*kx*mc;     R[1]=kx*ky*mc-kz*s;  R[2]=kx*kz*mc+ky*s;
      R[3]=ky*kx*mc+kz*s;  R[4]=c+ky*ky*mc;     R[5]=ky*kz*mc-kx*s;
      R[6]=kz*kx*mc-ky*s;  R[7]=kz*ky*mc+kx*s;  R[8]=c+kz*kz*mc;
    }
    const float gx=G0[3*t], gy=G0[3*t+1], gz=G0[3*t+2];
    const float tx=trans[3*t], ty=trans[3*t+1], tz=trans[3*t+2];
    float feat[32];
    #pragma unroll
    for (int i=0;i<9;i++) feat[i]=R[i];
    feat[9]  = gx + tx - (R[0]*gx + R[1]*gy + R[2]*gz);
    feat[10] = gy + ty - (R[3]*gx + R[4]*gy + R[5]*gz);
    feat[11] = gz + tz - (R[6]*gx + R[7]*gy + R[8]*gz);
    feat[12]=tx; feat[13]=ty; feat[14]=tz;
    feat[15]=1.0f;
    #pragma unroll
    for (int i=0;i<16;i++) feat[16+i] = wproj_w[i*MJ + t];
    #pragma unroll
    for (int f=0;f<32;f++) FT1[f*64 + t] = (_Float16)feat[f];
  }
  {
    float fold = b1[t];
    #pragma unroll
    for (int j=0;j<16;j++) fold = fmaf(w1[t*19 + 3 + j], wproj_b[j], fold);
    #pragma unroll
    for (int k=0;k<19;k++) FT2[t*32+k] = (_Float16)w1[t*19+k];
    FT2[t*32+19] = (_Float16)fold;
    #pragma unroll
    for (int k=20;k<32;k++) FT2[t*32+k] = (_Float16)0.0f;
  }
  for (int k=0;k<64;k++) FT3[t*64+k] = (_Float16)w2[t*64+k];
}

// 4 waves x 64 points (R24-verified structure, barriers -> fences):
// per-wave ping-pong LDS regions A,B; every phase reads one region, writes
// ONLY the other; phase order pinned by sched_barrier(0) only (no runtime
// barrier — all LDS deps are same-wave, HW DS pipe is in-order per wave).
//   P1: G1 reads global W, acc->B | P2: epilogue reads B, hin->A
//   P3: G2 reads A, h1->B | P4: G3 reads B, h2->A | P5: L3 reads A -> out
__global__ __launch_bounds__(256, 2)
void rig_main(const float* __restrict__ X0, const float* __restrict__ W,
              const _Float16* __restrict__ FT1, const _Float16* __restrict__ FT2,
              const _Float16* __restrict__ FT3,
              const float* __restrict__ b2, const float* __restrict__ w3,
              const float* __restrict__ b3,
              float* __restrict__ out, int Ntot) {
  __shared__ __align__(16) unsigned char smem[4*SLICE];   // 73728B
  const int tid  = threadIdx.x;
  const int wid  = tid >> 6;
  const int lane = tid & 63;
  const int lo   = lane & 15;
  const int hi   = lane >> 4;
  const int P0   = blockIdx.x * 256 + wid * 64;
  unsigned char* Areg = smem + wid * SLICE;
  unsigned char* Breg = Areg + REGSZ;

  const float x0 = X0[(size_t)(P0+lane)*3+0];
  const float x1 = X0[(size_t)(P0+lane)*3+1];
  const float x2 = X0[(size_t)(P0+lane)*3+2];

  // ---- P1: G1  C[feat 32][pt 64] = FT1(32x64) @ Wg^T, K=64 ; acc -> B
  //      B-fragment (pt,ks) = f16(W[P0+pt*16+lo][ks*32+hi*8 .. +7]) from global
  {
    f16x8 a1[2][2];
    #pragma unroll
    for (int ft=0; ft<2; ft++)
      #pragma unroll
      for (int ks=0; ks<2; ks++)
        a1[ft][ks] = *(const f16x8*)(FT1 + (ft*16+lo)*64 + ks*32 + hi*8);
    f32x4 acc[2][4];
    const f32x4 z = {0.f,0.f,0.f,0.f};
    #pragma unroll
    for (int ft=0; ft<2; ft++)
      #pragma unroll
      for (int pt=0; pt<4; pt++) acc[ft][pt] = z;

    const float* Wl = W + (size_t)(P0 + lo) * MJ + hi*8;
    #pragma unroll
    for (int pt=0; pt<4; pt++) {
      const float* Wp = Wl + (size_t)pt*16*MJ;
      f16x8 bf[2];
      #pragma unroll
      for (int ks=0; ks<2; ks++) {
        f32x4 q0 = *(const f32x4*)(Wp + ks*32);
        f32x4 q1 = *(const f32x4*)(Wp + ks*32 + 4);
        u32x4 pk;
        pk.x = pkhf(q0[0], q0[1]); pk.y = pkhf(q0[2], q0[3]);
        pk.z = pkhf(q1[0], q1[1]); pk.w = pkhf(q1[2], q1[3]);
        bf[ks] = __builtin_bit_cast(f16x8, pk);
      }
      #pragma unroll
      for (int ks=0; ks<2; ks++) {
        acc[0][pt] = mfma16(a1[0][ks], bf[ks], acc[0][pt]);
        acc[1][pt] = mfma16(a1[1][ks], bf[ks], acc[1][pt]);
      }
    }
    // D reg r of lane (hi,lo) = C[feat ft*16+hi*4+r][pt pt*16+lo] -> region B
    #pragma unroll
    for (int pt=0; pt<4; pt++)
      #pragma unroll
      for (int ft=0; ft<2; ft++)
        *(f32x4*)(Breg + (pt*16+lo)*STR + ft*64 + hi*16) = acc[ft][pt];
  }
  phase_fence();

  // ---- P2: per-point epilogue (reads B own row) -> hin f16 row in A
  float Rb[9], sk0, sk1, sk2;
  {
    float v[32];
    #pragma unroll
    for (int i=0;i<8;i++) {
      f32x4 t4 = *(const f32x4*)(Breg + lane*STR + i*16);
      v[4*i+0]=t4[0]; v[4*i+1]=t4[1]; v[4*i+2]=t4[2]; v[4*i+3]=t4[3];
    }
    const float inv = 1.0f/(v[15] + 1e-12f);
    #pragma unroll
    for (int i=0;i<9;i++) Rb[i]=v[i]*inv;
    const float cb0=v[9]*inv,  cb1=v[10]*inv, cb2=v[11]*inv;
    const float tb0=v[12]*inv, tb1=v[13]*inv, tb2=v[14]*inv;
    sk0 = fmaf(Rb[0],x0, fmaf(Rb[1],x1, fmaf(Rb[2],x2, cb0)));
    sk1 = fmaf(Rb[3],x0, fmaf(Rb[4],x1, fmaf(Rb[5],x2, cb1)));
    sk2 = fmaf(Rb[6],x0, fmaf(Rb[7],x1, fmaf(Rb[8],x2, cb2)));
    const float u0=sk0-tb0, u1=sk1-tb1, u2=sk2-tb2;
    const float l0 = Rb[0]*u0 + Rb[3]*u1 + Rb[6]*u2;
    const float l1 = Rb[1]*u0 + Rb[4]*u1 + Rb[7]*u2;
    const float l2 = Rb[2]*u0 + Rb[5]*u1 + Rb[8]*u2;
    float wf[16];
    #pragma unroll
    for (int j=0;j<16;j++) wf[j] = v[16+j]*inv;   // wproj_b folded into FT2 k=19
    u32x4 h0, h1v, h2v, h3;
    h0.x = pkhf(l0, l1);       h0.y = pkhf(l2, wf[0]);
    h0.z = pkhf(wf[1], wf[2]); h0.w = pkhf(wf[3], wf[4]);
    h1v.x = pkhf(wf[5], wf[6]);  h1v.y = pkhf(wf[7], wf[8]);
    h1v.z = pkhf(wf[9], wf[10]); h1v.w = pkhf(wf[11], wf[12]);
    h2v.x = pkhf(wf[13], wf[14]); h2v.y = pkhf(wf[15], 1.0f);
    h2v.z = 0u; h2v.w = 0u;
    h3.x = 0u; h3.y = 0u; h3.z = 0u; h3.w = 0u;
    phase_fence();   // B-reads stay above A-writes
    *(u32x4*)(Areg + lane*STR +  0) = h0;
    *(u32x4*)(Areg + lane*STR + 16) = h1v;
    *(u32x4*)(Areg + lane*STR + 32) = h2v;
    *(u32x4*)(Areg + lane*STR + 48) = h3;
  }
  phase_fence();

  // ---- P3: G2  h1[n 64][pt 64] = FT2(64x32) @ hin^T, K=32 ; h1 -> B
  {
    f16x8 bh[4];
    #pragma unroll
    for (int pt=0; pt<4; pt++)
      bh[pt] = *(const f16x8*)(Areg + (pt*16+lo)*STR + hi*16);
    #pragma unroll
    for (int nh=0; nh<2; nh++) {
      f16x8 a2[2];
      #pragma unroll
      for (int n2=0; n2<2; n2++)
        a2[n2] = *(const f16x8*)(FT2 + ((nh*2+n2)*16+lo)*32 + hi*8);
      f32x4 c2[2][4];
      const f32x4 z = {0.f,0.f,0.f,0.f};
      #pragma unroll
      for (int n2=0;n2<2;n2++)
        #pragma unroll
        for (int pt=0;pt<4;pt++) c2[n2][pt] = z;
      #pragma unroll
      for (int pt=0; pt<4; pt++)
        #pragma unroll
        for (int n2=0; n2<2; n2++)
          c2[n2][pt] = mfma16(a2[n2], bh[pt], c2[n2][pt]);
      #pragma unroll
      for (int n2=0; n2<2; n2++)
        #pragma unroll
        for (int pt=0; pt<4; pt++) {
          f32x4 r = c2[n2][pt];
          u32x2 wv;
          wv.x = pkhf(fmaxf(r[0],0.f), fmaxf(r[1],0.f));
          wv.y = pkhf(fmaxf(r[2],0.f), fmaxf(r[3],0.f));
          *(u32x2*)(Breg + (pt*16+lo)*STR + (nh*2+n2)*32 + hi*8) = wv;
        }
    }
  }
  phase_fence();

  // ---- P4: G3  h2[n 64][pt 64] = FT3(64x64) @ h1^T, K=64, +b2, relu ; h2 -> A
  {
    f16x8 bh1[4][2];
    #pragma unroll
    for (int pt=0; pt<4; pt++)
      #pragma unroll
      for (int ks=0; ks<2; ks++)
        bh1[pt][ks] = *(const f16x8*)(Breg + (pt*16+lo)*STR + ks*64 + hi*16);
    #pragma unroll
    for (int nh=0; nh<2; nh++) {
      f16x8 a3[2][2];
      #pragma unroll
      for (int n2=0; n2<2; n2++)
        #pragma unroll
        for (int ks=0; ks<2; ks++)
          a3[n2][ks] = *(const f16x8*)(FT3 + ((nh*2+n2)*16+lo)*64 + ks*32 + hi*8);
      f32x4 c3[2][4];
      const f32x4 z = {0.f,0.f,0.f,0.f};
      #pragma unroll
      for (int n2=0;n2<2;n2++)
        #pragma unroll
        for (int pt=0;pt<4;pt++) c3[n2][pt] = z;
      #pragma unroll
      for (int pt=0; pt<4; pt++)
        #pragma unroll
        for (int ks=0; ks<2; ks++)
          #pragma unroll
          for (int n2=0; n2<2; n2++)
            c3[n2][pt] = mfma16(a3[n2][ks], bh1[pt][ks], c3[n2][pt]);
      if (nh == 0) phase_fence();   // B-reads (bh1) stay above A-writes below
      #pragma unroll
      for (int n2=0; n2<2; n2++) {
        const f32x4 vb2 = *(const f32x4*)(b2 + (nh*2+n2)*16 + hi*4);
        #pragma unroll
        for (int pt=0; pt<4; pt++) {
          f32x4 r = c3[n2][pt];
          u32x2 wv;
          wv.x = pkhf(fmaxf(r[0]+vb2[0],0.f), fmaxf(r[1]+vb2[1],0.f));
          wv.y = pkhf(fmaxf(r[2]+vb2[2],0.f), fmaxf(r[3]+vb2[3],0.f));
          *(u32x2*)(Areg + (pt*16+lo)*STR + (nh*2+n2)*32 + hi*8) = wv;
        }
      }
    }
  }
  phase_fence();

  // ---- P5: scalar L3 (reads A own row; w3 wave-uniform -> s_load) + out
  {
    float d0 = b3[0], d1 = b3[1], d2 = b3[2];
    #pragma unroll
    for (int i8=0; i8<8; i8++) {
      f16x8 hv = *(const f16x8*)(Areg + lane*STR + i8*16);
      #pragma unroll
      for (int e=0; e<8; e++) {
        const float a = (float)hv[e];     // already relu'd
        const int j = i8*8 + e;
        d0 = fmaf(a, w3[      j], d0);
        d1 = fmaf(a, w3[ 64 + j], d1);
        d2 = fmaf(a, w3[128 + j], d2);
      }
    }
    const float dw0 = Rb[0]*d0 + Rb[1]*d1 + Rb[2]*d2;
    const float dw1 = Rb[3]*d0 + Rb[4]*d1 + Rb[5]*d2;
    const float dw2 = Rb[6]*d0 + Rb[7]*d1 + Rb[8]*d2;
    const size_t o = (size_t)(P0+lane)*3;
    out[o+0] = sk0 + dw0;
    out[o+1] = sk1 + dw1;
    out[o+2] = sk2 + dw2;
  }
}

extern "C" void kernel_launch(void* const* d_in, const int* in_sizes, int n_in,
                              void* d_out, int out_size, void* d_ws, size_t ws_size,
                              hipStream_t stream) {
  const float* X0      = (const float*)d_in[0];
  const float* G0      = (const float*)d_in[1];
  const float* W       = (const float*)d_in[2];
  const float* so3     = (const float*)d_in[3];
  const float* trans   = (const float*)d_in[4];
  const float* wproj_w = (const float*)d_in[5];
  const float* wproj_b = (const float*)d_in[6];
  const float* w1      = (const float*)d_in[7];
  const float* b1      = (const float*)d_in[8];
  const float* w2      = (const float*)d_in[9];
  const float* b2      = (const float*)d_in[10];
  const float* w3      = (const float*)d_in[11];
  const float* b3      = (const float*)d_in[12];
  float* out = (float*)d_out;

  const int Ntot = in_sizes[0] / 3;   // 262144

  _Float16* FT1 = (_Float16*)d_ws;                      // 4096B
  _Float16* FT2 = (_Float16*)((char*)d_ws + 4096);      // 4096B
  _Float16* FT3 = (_Float16*)((char*)d_ws + 8192);      // 8192B

  rig_prep<<<1, 64, 0, stream>>>(G0, so3, trans, wproj_w, wproj_b,
                                 w1, b1, w2, FT1, FT2, FT3);
  rig_main<<<Ntot/256, 256, 0, stream>>>(X0, W, FT1, FT2, FT3,
                                         b2, w3, b3, out, Ntot);
}